// Round 1
// baseline (860.213 us; speedup 1.0000x reference)
//
#include <hip/hip_runtime.h>
#include <stdint.h>

#define N_BATCH 8
#define A_ 3
#define H_ 336
#define W_ 336
#define HW_ (H_*W_)        // 112896
#define M_ (A_*HW_)        // 338688
#define K_TOP 2000
#define POST_N 1000
#define NMS_THR_ 0.7f
#define NEG_ (-1e9f)
#define VALID_THR_ (-5e8f)
#define CAND_CAP 8192
#define NBINS 16384
#define BIN_SHIFT 18
#define XCLIP 4.135166556742356f  // log(1000/16)

__device__ __forceinline__ unsigned int flip_key(float x) {
    unsigned int u = __float_as_uint(x);
    return (u & 0x80000000u) ? ~u : (u | 0x80000000u);
}

// ---------------- K1: per-batch 14-bit histogram of logit keys ----------------
__global__ void k_hist(const float* __restrict__ logits, unsigned int* __restrict__ ghist) {
    int n = blockIdx.y;
    int tid = blockIdx.x * blockDim.x + threadIdx.x;
    int stride = gridDim.x * blockDim.x;
    const float* lp = logits + (size_t)n * M_;
    unsigned int* h = ghist + (size_t)n * NBINS;
    for (int q = tid; q < M_; q += stride) {
        unsigned int u = flip_key(lp[q]);
        atomicAdd(&h[u >> BIN_SHIFT], 1u);
    }
}

// ---------------- K1b: find threshold bin B and countAbove per batch ----------------
__global__ void k_scan(const unsigned int* __restrict__ ghist, unsigned int* __restrict__ thresh) {
    int n = blockIdx.x;
    const unsigned int* h = ghist + (size_t)n * NBINS;
    __shared__ unsigned int part[256];
    __shared__ unsigned int scanb[256];
    int t = threadIdx.x;
    // chunk t covers bins [NBINS-64*(t+1), NBINS-64*t), i.e. descending chunks
    int hi = NBINS - 64 * t;
    int lo = hi - 64;
    unsigned int s = 0;
    for (int b = lo; b < hi; ++b) s += h[b];
    part[t] = s;
    scanb[t] = s;
    __syncthreads();
    for (int off = 1; off < 256; off <<= 1) {
        unsigned int v = scanb[t];
        unsigned int addv = (t >= off) ? scanb[t - off] : 0u;
        __syncthreads();
        scanb[t] = v + addv;
        __syncthreads();
    }
    unsigned int incl = scanb[t];
    unsigned int prefix = incl - part[t];
    if (prefix < K_TOP && incl >= K_TOP) {
        unsigned int acc = prefix;
        for (int b = hi - 1; b >= lo; --b) {
            unsigned int c = h[b];
            if (acc + c >= K_TOP) {
                thresh[n * 2 + 0] = (unsigned int)b;
                thresh[n * 2 + 1] = acc;
                break;
            }
            acc += c;
        }
    }
}

// ---------------- K2: compact candidates (bin >= B) as composite sort keys ----------------
__global__ void k_compact(const float* __restrict__ logits, const unsigned int* __restrict__ thresh,
                          unsigned int* __restrict__ cnt, unsigned long long* __restrict__ cand) {
    int n = blockIdx.y;
    unsigned int B = thresh[n * 2];
    int tid = blockIdx.x * blockDim.x + threadIdx.x;
    int stride = gridDim.x * blockDim.x;
    const float* lp = logits + (size_t)n * M_;
    unsigned long long* cp = cand + (size_t)n * CAND_CAP;
    for (int q = tid; q < M_; q += stride) {
        unsigned int u = flip_key(lp[q]);
        if ((u >> BIN_SHIFT) >= B) {
            int a = q / HW_;
            int hw = q - a * HW_;
            unsigned int m = (unsigned int)(hw * A_ + a);  // score-order index
            unsigned int pos = atomicAdd(&cnt[n], 1u);
            if (pos < CAND_CAP)
                cp[pos] = ((unsigned long long)u << 32) | (unsigned int)(~m);
        }
    }
}

// ---------------- K3: per-batch bitonic sort (descending), emit top-2000 indices ----------------
__global__ __launch_bounds__(512) void k_sort(const unsigned long long* __restrict__ cand,
                                              const unsigned int* __restrict__ cnt,
                                              unsigned int* __restrict__ top_m) {
    __shared__ unsigned long long sm[CAND_CAP];  // 64 KiB
    int n = blockIdx.x;
    unsigned int Cu = cnt[n];
    int C = (Cu < CAND_CAP) ? (int)Cu : CAND_CAP;
    const unsigned long long* cp = cand + (size_t)n * CAND_CAP;
    for (int i = threadIdx.x; i < CAND_CAP; i += 512)
        sm[i] = (i < C) ? cp[i] : 0ull;
    __syncthreads();
    for (int k = 2; k <= CAND_CAP; k <<= 1) {
        for (int j = k >> 1; j > 0; j >>= 1) {
            for (int i = threadIdx.x; i < CAND_CAP; i += 512) {
                int ixj = i ^ j;
                if (ixj > i) {
                    unsigned long long va = sm[i], vb = sm[ixj];
                    bool desc = ((i & k) == 0);
                    if (desc ? (va < vb) : (va > vb)) { sm[i] = vb; sm[ixj] = va; }
                }
            }
            __syncthreads();
        }
    }
    for (int i = threadIdx.x; i < K_TOP; i += 512)
        top_m[(size_t)n * K_TOP + i] = ~((unsigned int)sm[i]);
}

// ---------------- K4: decode + clip + validity for the top-2000 ----------------
__global__ void k_decode(const float* __restrict__ anchors, const float* __restrict__ logits,
                         const float* __restrict__ breg, const unsigned int* __restrict__ top_m,
                         float4* __restrict__ boxes, float* __restrict__ scores,
                         float* __restrict__ areas) {
    int g = blockIdx.x * blockDim.x + threadIdx.x;
    if (g >= N_BATCH * K_TOP) return;
    int n = g / K_TOP;
    unsigned int m = top_m[g];
    int a = (int)(m % 3u);
    int hw = (int)(m / 3u);
    float4 anc = ((const float4*)anchors)[(size_t)n * M_ + m];
    size_t rb = ((size_t)n * 12 + a * 4) * HW_ + hw;
    float dx = breg[rb];
    float dy = breg[rb + (size_t)HW_];
    float dw = breg[rb + (size_t)2 * HW_];
    float dh = breg[rb + (size_t)3 * HW_];
    float logit = logits[((size_t)n * 3 + a) * HW_ + hw];
    float score = 1.0f / (1.0f + expf(-logit));
    float w = anc.z - anc.x + 1.0f;
    float h = anc.w - anc.y + 1.0f;
    float cx = anc.x + 0.5f * w;
    float cy = anc.y + 0.5f * h;
    dw = fminf(dw, XCLIP);
    dh = fminf(dh, XCLIP);
    float pcx = dx * w + cx;
    float pcy = dy * h + cy;
    float pw = expf(dw) * w;
    float ph = expf(dh) * h;
    float x1 = pcx - 0.5f * pw;
    float y1 = pcy - 0.5f * ph;
    float x2 = pcx + 0.5f * pw - 1.0f;
    float y2 = pcy + 0.5f * ph - 1.0f;
    x1 = fminf(fmaxf(x1, 0.0f), 1332.0f);
    y1 = fminf(fmaxf(y1, 0.0f), 799.0f);
    x2 = fminf(fmaxf(x2, 0.0f), 1332.0f);
    y2 = fminf(fmaxf(y2, 0.0f), 799.0f);
    float ww = x2 - x1 + 1.0f;
    float hh = y2 - y1 + 1.0f;
    bool keep = (ww >= 0.0f) && (hh >= 0.0f);  // MIN_SIZE = 0
    boxes[g] = make_float4(x1, y1, x2, y2);
    scores[g] = keep ? score : NEG_;
    areas[g] = ww * hh;
}

// ---------------- K5: all-pairs IoU edge flags (any overlap > thr) ----------------
#define JCHUNK 500
__global__ void k_edges(const float4* __restrict__ boxes, const float* __restrict__ areas,
                        unsigned int* __restrict__ eflag) {
    int n = blockIdx.z;
    int chunk = blockIdx.y;
    int i = blockIdx.x * 256 + threadIdx.x;
    __shared__ float4 jb[JCHUNK];
    __shared__ float ja[JCHUNK];
    int j0 = chunk * JCHUNK;
    for (int j = threadIdx.x; j < JCHUNK; j += 256) {
        jb[j] = boxes[(size_t)n * K_TOP + j0 + j];
        ja[j] = areas[(size_t)n * K_TOP + j0 + j];
    }
    __syncthreads();
    if (i >= K_TOP) return;
    float4 bi = boxes[(size_t)n * K_TOP + i];
    float ai = areas[(size_t)n * K_TOP + i];
    bool any = false;
    for (int j = 0; j < JCHUNK; ++j) {
        int jj = j0 + j;
        if (jj == i) continue;
        float4 bj = jb[j];
        float xx1 = fmaxf(bi.x, bj.x);
        float yy1 = fmaxf(bi.y, bj.y);
        float xx2 = fminf(bi.z, bj.z);
        float yy2 = fminf(bi.w, bj.w);
        float inter = fmaxf(xx2 - xx1 + 1.0f, 0.0f) * fmaxf(yy2 - yy1 + 1.0f, 0.0f);
        float iou = inter / (ai + ja[j] - inter);
        any |= (iou > NMS_THR_);
    }
    if (any) atomicOr(&eflag[(size_t)n * K_TOP + i], 1u);
}

// ---------------- K6: sequential resolution on overlap subgraph + compaction + output ----------------
__global__ __launch_bounds__(256) void k_nms_out(const float4* __restrict__ boxes,
                                                 const float* __restrict__ scores,
                                                 const float* __restrict__ areas,
                                                 const unsigned int* __restrict__ eflag,
                                                 float* __restrict__ out) {
    int n = blockIdx.x;
    int tid = threadIdx.x;
    __shared__ float4 ibox[K_TOP];          // 32000 B
    __shared__ float iarea[K_TOP];          // 8000 B
    __shared__ unsigned short iidx[K_TOP];  // 4000 B
    __shared__ unsigned char ialive[K_TOP]; // 2000 B
    __shared__ unsigned char alive[K_TOP];  // 2000 B
    __shared__ unsigned int scanbuf[256];
    __shared__ int invTot;

    const float4* bb = boxes + (size_t)n * K_TOP;
    const float* ss = scores + (size_t)n * K_TOP;
    const float* aa = areas + (size_t)n * K_TOP;
    const unsigned int* ef = eflag + (size_t)n * K_TOP;

    // --- build involved list (order-preserving compaction of edge-flagged boxes) ---
    int i0 = tid * 8;
    unsigned int c = 0;
    for (int i = i0; i < i0 + 8; ++i) {
        alive[i] = (ss[i] > VALID_THR_) ? 1 : 0;
        c += (ef[i] != 0u) ? 1u : 0u;
    }
    scanbuf[tid] = c;
    __syncthreads();
    for (int off = 1; off < 256; off <<= 1) {
        unsigned int v = scanbuf[tid];
        unsigned int addv = (tid >= off) ? scanbuf[tid - off] : 0u;
        __syncthreads();
        scanbuf[tid] = v + addv;
        __syncthreads();
    }
    unsigned int excl = scanbuf[tid] - c;
    if (tid == 255) invTot = (int)scanbuf[255];
    unsigned int p = excl;
    for (int i = i0; i < i0 + 8; ++i) {
        if (ef[i] != 0u) {
            iidx[p] = (unsigned short)i;
            ibox[p] = bb[i];
            iarea[p] = aa[i];
            ialive[p] = alive[i];
            p++;
        }
    }
    __syncthreads();
    int IC = invTot;

    // --- sequential greedy resolution over involved boxes only ---
    for (int t = 0; t < IC; ++t) {
        __syncthreads();
        if (!ialive[t]) continue;  // block-uniform
        float4 bt = ibox[t];
        float at = iarea[t];
        for (int s = t + 1 + tid; s < IC; s += 256) {
            if (!ialive[s]) continue;
            float4 bs = ibox[s];
            float xx1 = fmaxf(bt.x, bs.x);
            float yy1 = fmaxf(bt.y, bs.y);
            float xx2 = fminf(bt.z, bs.z);
            float yy2 = fminf(bt.w, bs.w);
            float inter = fmaxf(xx2 - xx1 + 1.0f, 0.0f) * fmaxf(yy2 - yy1 + 1.0f, 0.0f);
            float iou = inter / (at + iarea[s] - inter);
            if (iou > NMS_THR_) ialive[s] = 0;
        }
    }
    __syncthreads();
    for (int s = tid; s < IC; s += 256) alive[iidx[s]] = ialive[s];
    __syncthreads();

    // --- order-preserving compaction of survivors -> output rows ---
    unsigned int c2 = 0;
    for (int i = i0; i < i0 + 8; ++i) c2 += alive[i];
    scanbuf[tid] = c2;
    __syncthreads();
    for (int off = 1; off < 256; off <<= 1) {
        unsigned int v = scanbuf[tid];
        unsigned int addv = (tid >= off) ? scanbuf[tid - off] : 0u;
        __syncthreads();
        scanbuf[tid] = v + addv;
        __syncthreads();
    }
    unsigned int r = scanbuf[tid] - c2;
    unsigned int total = scanbuf[255];
    float* op = out + (size_t)n * POST_N * 5;
    for (int i = i0; i < i0 + 8; ++i) {
        if (alive[i]) {
            if (r < POST_N) {
                float4 b = bb[i];
                op[r * 5 + 0] = b.x;
                op[r * 5 + 1] = b.y;
                op[r * 5 + 2] = b.z;
                op[r * 5 + 3] = b.w;
                op[r * 5 + 4] = ss[i];
            }
            r++;
        }
    }
    unsigned int S = (total > POST_N) ? POST_N : total;
    for (unsigned int q = S + tid; q < POST_N; q += 256) {
        op[q * 5 + 0] = 0.0f;
        op[q * 5 + 1] = 0.0f;
        op[q * 5 + 2] = 0.0f;
        op[q * 5 + 3] = 0.0f;
        op[q * 5 + 4] = 0.0f;
    }
}

extern "C" void kernel_launch(void* const* d_in, const int* in_sizes, int n_in,
                              void* d_out, int out_size, void* d_ws, size_t ws_size,
                              hipStream_t stream) {
    const float* anchors = (const float*)d_in[0];
    const float* logits  = (const float*)d_in[1];
    const float* breg    = (const float*)d_in[2];
    float* out = (float*)d_out;
    char* ws = (char*)d_ws;

    // ws layout (bytes):
    // [0, 524288)            ghist  : u32[8][16384]   (zeroed)
    // [524288, 524320)       cnt    : u32[8]          (zeroed)
    // [524320, 588320)       eflag  : u32[8][2000]    (zeroed)
    // [588352, 588416)       thresh : u32[8][2]
    // [588416, 1112704)      cand   : u64[8][8192]
    // [1112704, 1176704)     top_m  : u32[8][2000]
    // [1176704, 1432704)     boxes  : float4[8][2000]
    // [1432704, 1496704)     scores : f32[8][2000]
    // [1496704, 1560704)     areas  : f32[8][2000]
    unsigned int* ghist        = (unsigned int*)(ws);
    unsigned int* cnt          = (unsigned int*)(ws + 524288);
    unsigned int* eflag        = (unsigned int*)(ws + 524320);
    unsigned int* thresh       = (unsigned int*)(ws + 588352);
    unsigned long long* cand   = (unsigned long long*)(ws + 588416);
    unsigned int* top_m        = (unsigned int*)(ws + 1112704);
    float4* boxes              = (float4*)(ws + 1176704);
    float* scores              = (float*)(ws + 1432704);
    float* areas               = (float*)(ws + 1496704);

    hipMemsetAsync(ws, 0, 588320, stream);

    k_hist<<<dim3(32, 8), 256, 0, stream>>>(logits, ghist);
    k_scan<<<8, 256, 0, stream>>>(ghist, thresh);
    k_compact<<<dim3(32, 8), 256, 0, stream>>>(logits, thresh, cnt, cand);
    k_sort<<<8, 512, 0, stream>>>(cand, cnt, top_m);
    k_decode<<<(N_BATCH * K_TOP + 255) / 256, 256, 0, stream>>>(anchors, logits, breg, top_m,
                                                                boxes, scores, areas);
    k_edges<<<dim3(8, 4, 8), 256, 0, stream>>>(boxes, areas, eflag);
    k_nms_out<<<8, 256, 0, stream>>>(boxes, scores, areas, eflag, out);
}

// Round 2
// 516.513 us; speedup vs baseline: 1.6654x; 1.6654x over previous
//
#include <hip/hip_runtime.h>
#include <stdint.h>

#define N_BATCH 8
#define A_ 3
#define H_ 336
#define W_ 336
#define HW_ (H_*W_)        // 112896
#define M_ (A_*HW_)        // 338688
#define K_TOP 2000
#define POST_N 1000
#define NMS_THR_ 0.7f
#define NEG_ (-1e9f)
#define VALID_THR_ (-5e8f)
#define CAND_CAP 4096
#define NBINS 4096
#define BIN_SHIFT 20       // top 12 bits: sign+exp+3 mantissa
#define HBLK 8             // histogram blocks per batch
#define XCLIP 4.135166556742356f  // log(1000/16)

__device__ __forceinline__ unsigned int flip_key(float x) {
    unsigned int u = __float_as_uint(x);
    return (u & 0x80000000u) ? ~u : (u | 0x80000000u);
}
__device__ __forceinline__ float unflip_key(unsigned int k) {
    unsigned int u = (k & 0x80000000u) ? (k & 0x7fffffffu) : ~k;
    return __uint_as_float(u);
}

// ---------------- K1: per-block LDS histogram -> private global region (no atomics) ----------------
__global__ __launch_bounds__(256) void k_hist(const float* __restrict__ logits,
                                              unsigned int* __restrict__ ghist) {
    __shared__ unsigned int h[NBINS];  // 16 KiB
    int n = blockIdx.y, b = blockIdx.x;
    for (int i = threadIdx.x; i < NBINS; i += 256) h[i] = 0;
    __syncthreads();
    const int seg = M_ / HBLK;               // 42336
    const float4* lp = (const float4*)(logits + (size_t)n * M_ + (size_t)b * seg);
    const int nq = seg / 4;                  // 10584
    for (int q = threadIdx.x; q < nq; q += 256) {
        float4 v = lp[q];
        atomicAdd(&h[flip_key(v.x) >> BIN_SHIFT], 1u);
        atomicAdd(&h[flip_key(v.y) >> BIN_SHIFT], 1u);
        atomicAdd(&h[flip_key(v.z) >> BIN_SHIFT], 1u);
        atomicAdd(&h[flip_key(v.w) >> BIN_SHIFT], 1u);
    }
    __syncthreads();
    unsigned int* gp = ghist + ((size_t)n * HBLK + b) * NBINS;
    for (int i = threadIdx.x; i < NBINS; i += 256) gp[i] = h[i];
}

// ---------------- K1b: sum sub-hists, find threshold bin B per batch ----------------
__global__ __launch_bounds__(256) void k_scan(const unsigned int* __restrict__ ghist,
                                              unsigned int* __restrict__ thresh) {
    int n = blockIdx.x;
    int t = threadIdx.x;
    __shared__ unsigned int binsum[NBINS];
    __shared__ unsigned int part[256];
    __shared__ unsigned int scanb[256];
    const unsigned int* base = ghist + (size_t)n * HBLK * NBINS;
    for (int i = t; i < NBINS; i += 256) {
        unsigned int s = 0;
        for (int b = 0; b < HBLK; ++b) s += base[(size_t)b * NBINS + i];
        binsum[i] = s;
    }
    __syncthreads();
    // chunk t covers bins [NBINS-16*(t+1), NBINS-16*t) — descending chunks
    int hi = NBINS - 16 * t;
    int lo = hi - 16;
    unsigned int s = 0;
    for (int b = lo; b < hi; ++b) s += binsum[b];
    part[t] = s;
    scanb[t] = s;
    __syncthreads();
    for (int off = 1; off < 256; off <<= 1) {
        unsigned int v = scanb[t];
        unsigned int addv = (t >= off) ? scanb[t - off] : 0u;
        __syncthreads();
        scanb[t] = v + addv;
        __syncthreads();
    }
    unsigned int incl = scanb[t];
    unsigned int prefix = incl - part[t];
    if (prefix < K_TOP && incl >= K_TOP) {
        unsigned int acc = prefix;
        for (int b = hi - 1; b >= lo; --b) {
            unsigned int c = binsum[b];
            if (acc + c >= K_TOP) {
                thresh[n] = (unsigned int)b;
                break;
            }
            acc += c;
        }
    }
}

// ---------------- K2: compact candidates (bin >= B) as composite u64 keys ----------------
__global__ __launch_bounds__(256) void k_compact(const float* __restrict__ logits,
                                                 const unsigned int* __restrict__ thresh,
                                                 unsigned int* __restrict__ cnt,
                                                 unsigned long long* __restrict__ cand) {
    int n = blockIdx.y, b = blockIdx.x;
    unsigned int B = thresh[n];
    const int seg = M_ / HBLK;
    const int qbase = b * seg;
    const float4* lp = (const float4*)(logits + (size_t)n * M_ + (size_t)qbase);
    const int nq = seg / 4;
    unsigned long long* cp = cand + (size_t)n * CAND_CAP;
    for (int q = threadIdx.x; q < nq; q += 256) {
        float4 v = lp[q];
        float vv[4] = {v.x, v.y, v.z, v.w};
        #pragma unroll
        for (int e = 0; e < 4; ++e) {
            unsigned int u = flip_key(vv[e]);
            if ((u >> BIN_SHIFT) >= B) {
                int qq = qbase + q * 4 + e;
                int a = qq / HW_;
                int hw = qq - a * HW_;
                unsigned int m = (unsigned int)(hw * A_ + a);  // score-order index
                unsigned int pos = atomicAdd(&cnt[n], 1u);
                if (pos < CAND_CAP)
                    cp[pos] = ((unsigned long long)u << 32) | (unsigned int)(~m);
            }
        }
    }
}

// ---------------- K3: per-batch bitonic sort of 4096 (descending), emit top-2000 keys ----------------
__global__ __launch_bounds__(1024) void k_sort(const unsigned long long* __restrict__ cand,
                                               const unsigned int* __restrict__ cnt,
                                               unsigned long long* __restrict__ topkv) {
    __shared__ unsigned long long sm[CAND_CAP];  // 32 KiB
    int n = blockIdx.x;
    unsigned int Cu = cnt[n];
    int C = (Cu < CAND_CAP) ? (int)Cu : CAND_CAP;
    const unsigned long long* cp = cand + (size_t)n * CAND_CAP;
    for (int i = threadIdx.x; i < CAND_CAP; i += 1024)
        sm[i] = (i < C) ? cp[i] : 0ull;
    __syncthreads();
    for (int k = 2; k <= CAND_CAP; k <<= 1) {
        for (int j = k >> 1; j > 0; j >>= 1) {
            for (int i = threadIdx.x; i < CAND_CAP; i += 1024) {
                int ixj = i ^ j;
                if (ixj > i) {
                    unsigned long long va = sm[i], vb = sm[ixj];
                    bool desc = ((i & k) == 0);
                    if (desc ? (va < vb) : (va > vb)) { sm[i] = vb; sm[ixj] = va; }
                }
            }
            __syncthreads();
        }
    }
    for (int i = threadIdx.x; i < K_TOP; i += 1024)
        topkv[(size_t)n * K_TOP + i] = sm[i];
}

// ---------------- K4: decode + clip + validity for the top-2000 ----------------
__global__ __launch_bounds__(256) void k_decode(const float* __restrict__ anchors,
                                                const float* __restrict__ breg,
                                                const unsigned long long* __restrict__ topkv,
                                                float4* __restrict__ boxes,
                                                float* __restrict__ scores,
                                                float* __restrict__ areas) {
    int g = blockIdx.x * blockDim.x + threadIdx.x;
    if (g >= N_BATCH * K_TOP) return;
    int n = g / K_TOP;
    unsigned long long kv = topkv[g];
    unsigned int u = (unsigned int)(kv >> 32);
    unsigned int m = ~((unsigned int)kv);
    float logit = unflip_key(u);
    int a = (int)(m % 3u);
    int hw = (int)(m / 3u);
    float4 anc = ((const float4*)anchors)[(size_t)n * M_ + m];
    size_t rb = ((size_t)n * 12 + a * 4) * HW_ + hw;
    float dx = breg[rb];
    float dy = breg[rb + (size_t)HW_];
    float dw = breg[rb + (size_t)2 * HW_];
    float dh = breg[rb + (size_t)3 * HW_];
    float score = 1.0f / (1.0f + expf(-logit));
    float w = anc.z - anc.x + 1.0f;
    float h = anc.w - anc.y + 1.0f;
    float cx = anc.x + 0.5f * w;
    float cy = anc.y + 0.5f * h;
    dw = fminf(dw, XCLIP);
    dh = fminf(dh, XCLIP);
    float pcx = dx * w + cx;
    float pcy = dy * h + cy;
    float pw = expf(dw) * w;
    float ph = expf(dh) * h;
    float x1 = pcx - 0.5f * pw;
    float y1 = pcy - 0.5f * ph;
    float x2 = pcx + 0.5f * pw - 1.0f;
    float y2 = pcy + 0.5f * ph - 1.0f;
    x1 = fminf(fmaxf(x1, 0.0f), 1332.0f);
    y1 = fminf(fmaxf(y1, 0.0f), 799.0f);
    x2 = fminf(fmaxf(x2, 0.0f), 1332.0f);
    y2 = fminf(fmaxf(y2, 0.0f), 799.0f);
    float ww = x2 - x1 + 1.0f;
    float hh = y2 - y1 + 1.0f;
    bool keep = (ww >= 0.0f) && (hh >= 0.0f);  // MIN_SIZE = 0
    boxes[g] = make_float4(x1, y1, x2, y2);
    scores[g] = keep ? score : NEG_;
    areas[g] = ww * hh;
}

// ---------------- K5: all-pairs IoU edge flags (any overlap > thr) ----------------
#define JCHUNK 500
__global__ __launch_bounds__(256) void k_edges(const float4* __restrict__ boxes,
                                               const float* __restrict__ areas,
                                               unsigned int* __restrict__ eflag) {
    int n = blockIdx.z;
    int chunk = blockIdx.y;
    int i = blockIdx.x * 256 + threadIdx.x;
    __shared__ float4 jb[JCHUNK];
    __shared__ float ja[JCHUNK];
    int j0 = chunk * JCHUNK;
    for (int j = threadIdx.x; j < JCHUNK; j += 256) {
        jb[j] = boxes[(size_t)n * K_TOP + j0 + j];
        ja[j] = areas[(size_t)n * K_TOP + j0 + j];
    }
    __syncthreads();
    if (i >= K_TOP) return;
    float4 bi = boxes[(size_t)n * K_TOP + i];
    float ai = areas[(size_t)n * K_TOP + i];
    bool any = false;
    for (int j = 0; j < JCHUNK; ++j) {
        int jj = j0 + j;
        if (jj == i) continue;
        float4 bj = jb[j];
        float xx1 = fmaxf(bi.x, bj.x);
        float yy1 = fmaxf(bi.y, bj.y);
        float xx2 = fminf(bi.z, bj.z);
        float yy2 = fminf(bi.w, bj.w);
        float inter = fmaxf(xx2 - xx1 + 1.0f, 0.0f) * fmaxf(yy2 - yy1 + 1.0f, 0.0f);
        float iou = inter / (ai + ja[j] - inter);
        any |= (iou > NMS_THR_);
    }
    if (any) atomicOr(&eflag[(size_t)n * K_TOP + i], 1u);
}

// ---------------- K6: sequential resolution on overlap subgraph + compaction + output ----------------
__global__ __launch_bounds__(256) void k_nms_out(const float4* __restrict__ boxes,
                                                 const float* __restrict__ scores,
                                                 const float* __restrict__ areas,
                                                 const unsigned int* __restrict__ eflag,
                                                 float* __restrict__ out) {
    int n = blockIdx.x;
    int tid = threadIdx.x;
    __shared__ float4 ibox[K_TOP];          // 32000 B
    __shared__ float iarea[K_TOP];          // 8000 B
    __shared__ unsigned short iidx[K_TOP];  // 4000 B
    __shared__ unsigned char ialive[K_TOP]; // 2000 B
    __shared__ unsigned char alive[K_TOP];  // 2000 B
    __shared__ unsigned int scanbuf[256];
    __shared__ int invTot;

    const float4* bb = boxes + (size_t)n * K_TOP;
    const float* ss = scores + (size_t)n * K_TOP;
    const float* aa = areas + (size_t)n * K_TOP;
    const unsigned int* ef = eflag + (size_t)n * K_TOP;

    // --- build involved list (order-preserving compaction of edge-flagged boxes) ---
    int i0 = tid * 8;
    unsigned int c = 0;
    for (int i = i0; i < i0 + 8; ++i) {
        alive[i] = (ss[i] > VALID_THR_) ? 1 : 0;
        c += (ef[i] != 0u) ? 1u : 0u;
    }
    scanbuf[tid] = c;
    __syncthreads();
    for (int off = 1; off < 256; off <<= 1) {
        unsigned int v = scanbuf[tid];
        unsigned int addv = (tid >= off) ? scanbuf[tid - off] : 0u;
        __syncthreads();
        scanbuf[tid] = v + addv;
        __syncthreads();
    }
    unsigned int excl = scanbuf[tid] - c;
    if (tid == 255) invTot = (int)scanbuf[255];
    unsigned int p = excl;
    for (int i = i0; i < i0 + 8; ++i) {
        if (ef[i] != 0u) {
            iidx[p] = (unsigned short)i;
            ibox[p] = bb[i];
            iarea[p] = aa[i];
            ialive[p] = alive[i];
            p++;
        }
    }
    __syncthreads();
    int IC = invTot;

    // --- sequential greedy resolution over involved boxes only ---
    for (int t = 0; t < IC; ++t) {
        __syncthreads();
        if (!ialive[t]) continue;  // block-uniform
        float4 bt = ibox[t];
        float at = iarea[t];
        for (int s = t + 1 + tid; s < IC; s += 256) {
            if (!ialive[s]) continue;
            float4 bs = ibox[s];
            float xx1 = fmaxf(bt.x, bs.x);
            float yy1 = fmaxf(bt.y, bs.y);
            float xx2 = fminf(bt.z, bs.z);
            float yy2 = fminf(bt.w, bs.w);
            float inter = fmaxf(xx2 - xx1 + 1.0f, 0.0f) * fmaxf(yy2 - yy1 + 1.0f, 0.0f);
            float iou = inter / (at + iarea[s] - inter);
            if (iou > NMS_THR_) ialive[s] = 0;
        }
    }
    __syncthreads();
    for (int s = tid; s < IC; s += 256) alive[iidx[s]] = ialive[s];
    __syncthreads();

    // --- order-preserving compaction of survivors -> output rows ---
    unsigned int c2 = 0;
    for (int i = i0; i < i0 + 8; ++i) c2 += alive[i];
    scanbuf[tid] = c2;
    __syncthreads();
    for (int off = 1; off < 256; off <<= 1) {
        unsigned int v = scanbuf[tid];
        unsigned int addv = (tid >= off) ? scanbuf[tid - off] : 0u;
        __syncthreads();
        scanbuf[tid] = v + addv;
        __syncthreads();
    }
    unsigned int r = scanbuf[tid] - c2;
    unsigned int total = scanbuf[255];
    float* op = out + (size_t)n * POST_N * 5;
    for (int i = i0; i < i0 + 8; ++i) {
        if (alive[i]) {
            if (r < POST_N) {
                float4 b = bb[i];
                op[r * 5 + 0] = b.x;
                op[r * 5 + 1] = b.y;
                op[r * 5 + 2] = b.z;
                op[r * 5 + 3] = b.w;
                op[r * 5 + 4] = ss[i];
            }
            r++;
        }
    }
    unsigned int S = (total > POST_N) ? POST_N : total;
    for (unsigned int q = S + tid; q < POST_N; q += 256) {
        op[q * 5 + 0] = 0.0f;
        op[q * 5 + 1] = 0.0f;
        op[q * 5 + 2] = 0.0f;
        op[q * 5 + 3] = 0.0f;
        op[q * 5 + 4] = 0.0f;
    }
}

extern "C" void kernel_launch(void* const* d_in, const int* in_sizes, int n_in,
                              void* d_out, int out_size, void* d_ws, size_t ws_size,
                              hipStream_t stream) {
    const float* anchors = (const float*)d_in[0];
    const float* logits  = (const float*)d_in[1];
    const float* breg    = (const float*)d_in[2];
    float* out = (float*)d_out;
    char* ws = (char*)d_ws;

    // ws layout (bytes):
    // [0, 32)                cnt    : u32[8]              (zeroed)
    // [32, 64032)            eflag  : u32[8][2000]        (zeroed)
    // [64064, 1112640)       ghist  : u32[8][HBLK][4096]  (fully written, no zero)
    // [1112640, 1112704)     thresh : u32[8]
    // [1112704, 1374848)     cand   : u64[8][4096]
    // [1374848, 1502848)     topkv  : u64[8][2000]
    // [1502848, 1758848)     boxes  : float4[8][2000]
    // [1758848, 1822848)     scores : f32[8][2000]
    // [1822848, 1886848)     areas  : f32[8][2000]
    unsigned int* cnt          = (unsigned int*)(ws);
    unsigned int* eflag        = (unsigned int*)(ws + 32);
    unsigned int* ghist        = (unsigned int*)(ws + 64064);
    unsigned int* thresh       = (unsigned int*)(ws + 1112640);
    unsigned long long* cand   = (unsigned long long*)(ws + 1112704);
    unsigned long long* topkv  = (unsigned long long*)(ws + 1374848);
    float4* boxes              = (float4*)(ws + 1502848);
    float* scores              = (float*)(ws + 1758848);
    float* areas               = (float*)(ws + 1822848);

    hipMemsetAsync(ws, 0, 64032, stream);

    k_hist<<<dim3(HBLK, 8), 256, 0, stream>>>(logits, ghist);
    k_scan<<<8, 256, 0, stream>>>(ghist, thresh);
    k_compact<<<dim3(HBLK, 8), 256, 0, stream>>>(logits, thresh, cnt, cand);
    k_sort<<<8, 1024, 0, stream>>>(cand, cnt, topkv);
    k_decode<<<(N_BATCH * K_TOP + 255) / 256, 256, 0, stream>>>(anchors, breg, topkv,
                                                                boxes, scores, areas);
    k_edges<<<dim3(8, 4, 8), 256, 0, stream>>>(boxes, areas, eflag);
    k_nms_out<<<8, 256, 0, stream>>>(boxes, scores, areas, eflag, out);
}